// Round 1
// baseline (175.370 us; speedup 1.0000x reference)
//
#include <hip/hip_runtime.h>
#include <math.h>

// Problem constants (from reference)
#define N_SAMPLES 32768
#define N_FRAMES  128
#define N_EVENTS  16
#define MODEL_DIM 128
#define N_FREQS   16
#define POS_DIM   33          // 2*16 + 1
#define N_ROWS    512         // B*E = 32*16

// ws layout: [0, 128*33*4) pos_hat floats ; at byte offset 32768: int d[512]
// total ws needed: 32768 + 2048 bytes

// ---------------------------------------------------------------------------
// Kernel 1: build normalized positional encodings (128 x 33), replicating
// numpy: x = float32(linspace(-pi, pi, 128)); feats = [x, sin(2^i x), cos(2^i x)]
// computed at float32 argument (2^i * x is EXACT in f32 — power-of-two scale),
// sin/cos in double then rounded to f32 (matches numpy within ~1 ulp f32).
// ---------------------------------------------------------------------------
__global__ __launch_bounds__(128) void pos_kernel(float* __restrict__ pos_hat) {
    int f = threadIdx.x;                       // 0..127
    double step = (2.0 * M_PI) / 127.0;        // numpy linspace step in double
    double xd = -M_PI + (double)f * step;
    if (f == N_FRAMES - 1) xd = M_PI;          // linspace sets endpoint exactly
    float x = (float)xd;

    float feat[POS_DIM];
    feat[0] = x;
    double xdub = (double)x;
    for (int i = 0; i < N_FREQS; ++i) {
        double arg = ldexp(xdub, i);           // x * 2^i, exact
        feat[1 + 2 * i] = (float)sin(arg);
        feat[2 + 2 * i] = (float)cos(arg);
    }
    double nrm = 0.0;
    for (int j = 0; j < POS_DIM; ++j) nrm += (double)feat[j] * (double)feat[j];
    float inv = 1.0f / ((float)sqrt(nrm) + 1e-8f);
    for (int j = 0; j < POS_DIM; ++j) pos_hat[f * POS_DIM + j] = feat[j] * inv;
}

// ---------------------------------------------------------------------------
// Kernel 2: per row (512 of them): p = TL_row @ W + b  (33 vals, double acc),
// then argmax over 128 frames of dot(p, pos_hat[f]) (double acc).
// p's own normalization is a positive per-row scalar -> argmax-invariant.
// Tie-break: lowest frame index (jnp.argmax takes first occurrence).
// ---------------------------------------------------------------------------
__global__ __launch_bounds__(128) void argmax_kernel(
    const float* __restrict__ tl,        // (512,128)
    const float* __restrict__ W,         // (128,33) row-major
    const float* __restrict__ b,         // (33)
    const float* __restrict__ pos_hat,   // (128,33)
    int* __restrict__ dout)              // (512) -> argmax*256
{
    __shared__ float  s_tl[MODEL_DIM];
    __shared__ float  s_p[POS_DIM];
    __shared__ double sv[N_FRAMES];
    __shared__ int    si[N_FRAMES];

    int row = blockIdx.x;
    int t = threadIdx.x;

    s_tl[t] = tl[(size_t)row * MODEL_DIM + t];
    __syncthreads();

    if (t < POS_DIM) {
        double acc = (double)b[t];
        for (int k = 0; k < MODEL_DIM; ++k)
            acc += (double)s_tl[k] * (double)W[k * POS_DIM + t];
        s_p[t] = (float)acc;
    }
    __syncthreads();

    double s = 0.0;
    for (int j = 0; j < POS_DIM; ++j)
        s += (double)s_p[j] * (double)pos_hat[t * POS_DIM + j];

    sv[t] = s;
    si[t] = t;
    __syncthreads();

    for (int off = 64; off > 0; off >>= 1) {
        if (t < off) {
            double ov = sv[t + off];
            int    oi = si[t + off];
            if (ov > sv[t] || (ov == sv[t] && oi < si[t])) {
                sv[t] = ov;
                si[t] = oi;
            }
        }
        __syncthreads();
    }
    if (t == 0) dout[row] = si[0] * (N_SAMPLES / N_FRAMES);
}

// ---------------------------------------------------------------------------
// Kernel 3: out[row, t] = (t >= d) ? stems[row, t-d] / 256 : 0
// d is a multiple of 256, t walks in aligned float4 chunks -> both sides stay
// 16B-aligned; each 4-chunk is entirely before or after d.
// ---------------------------------------------------------------------------
__global__ __launch_bounds__(256) void shift_kernel(
    const float* __restrict__ stems,     // (512, 32768)
    const int*   __restrict__ dvals,     // (512)
    float*       __restrict__ out)       // (512, 32768)
{
    int row = blockIdx.y;
    int t = (blockIdx.x * 256 + threadIdx.x) * 4;
    int d = dvals[row];

    const float4* src = (const float4*)(stems + (size_t)row * N_SAMPLES);
    float4*       dst = (float4*)(out + (size_t)row * N_SAMPLES);

    float4 v;
    if (t >= d) {
        v = src[(t - d) >> 2];
        const float sc = 1.0f / 256.0f;
        v.x *= sc; v.y *= sc; v.z *= sc; v.w *= sc;
    } else {
        v = make_float4(0.f, 0.f, 0.f, 0.f);
    }
    dst[t >> 2] = v;
}

extern "C" void kernel_launch(void* const* d_in, const int* in_sizes, int n_in,
                              void* d_out, int out_size, void* d_ws, size_t ws_size,
                              hipStream_t stream) {
    const float* tl    = (const float*)d_in[0];  // time_latent (512,128)
    const float* stems = (const float*)d_in[1];  // (32,16,32768)
    // d_in[2] = targets — unused by the reference
    const float* W     = (const float*)d_in[3];  // (128,33)
    const float* b     = (const float*)d_in[4];  // (33)
    float* out = (float*)d_out;

    float* pos_hat = (float*)d_ws;
    int*   dvals   = (int*)((char*)d_ws + 32768);

    pos_kernel<<<1, 128, 0, stream>>>(pos_hat);
    argmax_kernel<<<N_ROWS, 128, 0, stream>>>(tl, W, b, pos_hat, dvals);
    shift_kernel<<<dim3(N_SAMPLES / (256 * 4), N_ROWS), 256, 0, stream>>>(stems, dvals, out);
}

// Round 2
// 169.721 us; speedup vs baseline: 1.0333x; 1.0333x over previous
//
#include <hip/hip_runtime.h>
#include <math.h>

// Problem constants (from reference)
#define N_SAMPLES 32768
#define N_FRAMES  128
#define N_EVENTS  16
#define MODEL_DIM 128
#define N_FREQS   16
#define POS_DIM   33          // 2*16 + 1
#define N_ROWS    512         // B*E = 32*16

// ws layout: [0, 128*33*4) pos_hat floats ; at byte offset 32768: int d[512]

// ---------------------------------------------------------------------------
// Kernel 1: normalized positional encodings (128 x 33).
// One block per frame; lane j computes exactly ONE feature (one double sin/cos)
// -> single-transcendental latency across 128 CUs instead of 32 serial
// transcendentals on one CU (previous version: 99.8 us -> expect ~3 us).
// Numerics identical to numpy path: x = f32(linspace(-pi,pi,128)) computed in
// double; arg = 2^i * x exact via ldexp; sin/cos in double, round to f32.
// ---------------------------------------------------------------------------
__global__ __launch_bounds__(64) void pos_kernel(float* __restrict__ pos_hat) {
    int f = blockIdx.x;                        // frame 0..127
    int j = threadIdx.x;                       // feature 0..32 (33..63 idle)

    __shared__ float s_feat[POS_DIM];
    __shared__ float s_inv;

    double step = (2.0 * M_PI) / 127.0;
    double xd = -M_PI + (double)f * step;
    if (f == N_FRAMES - 1) xd = M_PI;          // linspace endpoint exact
    float x = (float)xd;

    if (j < POS_DIM) {
        float v;
        if (j == 0) {
            v = x;
        } else {
            int i = (j - 1) >> 1;              // frequency index
            double arg = ldexp((double)x, i);  // x * 2^i, exact
            v = (j & 1) ? (float)sin(arg) : (float)cos(arg);
        }
        s_feat[j] = v;
    }
    __syncthreads();

    if (j == 0) {
        double nrm = 0.0;
        for (int k = 0; k < POS_DIM; ++k)
            nrm += (double)s_feat[k] * (double)s_feat[k];
        s_inv = 1.0f / ((float)sqrt(nrm) + 1e-8f);
    }
    __syncthreads();

    if (j < POS_DIM) pos_hat[f * POS_DIM + j] = s_feat[j] * s_inv;
}

// ---------------------------------------------------------------------------
// Kernel 2: per row (512): p = TL_row @ W + b (33 vals, double acc), then
// argmax over 128 frames of dot(p, pos_hat[f]) (double acc). p's own
// normalization is a positive scalar -> argmax-invariant. Tie-break: lowest
// frame index (jnp.argmax first occurrence).
// ---------------------------------------------------------------------------
__global__ __launch_bounds__(128) void argmax_kernel(
    const float* __restrict__ tl,        // (512,128)
    const float* __restrict__ W,         // (128,33) row-major
    const float* __restrict__ b,         // (33)
    const float* __restrict__ pos_hat,   // (128,33)
    int* __restrict__ dout)              // (512) -> argmax*256
{
    __shared__ float  s_tl[MODEL_DIM];
    __shared__ float  s_p[POS_DIM];
    __shared__ double sv[N_FRAMES];
    __shared__ int    si[N_FRAMES];

    int row = blockIdx.x;
    int t = threadIdx.x;

    s_tl[t] = tl[(size_t)row * MODEL_DIM + t];
    __syncthreads();

    if (t < POS_DIM) {
        double acc = (double)b[t];
        for (int k = 0; k < MODEL_DIM; ++k)
            acc += (double)s_tl[k] * (double)W[k * POS_DIM + t];
        s_p[t] = (float)acc;
    }
    __syncthreads();

    double s = 0.0;
    for (int j = 0; j < POS_DIM; ++j)
        s += (double)s_p[j] * (double)pos_hat[t * POS_DIM + j];

    sv[t] = s;
    si[t] = t;
    __syncthreads();

    for (int off = 64; off > 0; off >>= 1) {
        if (t < off) {
            double ov = sv[t + off];
            int    oi = si[t + off];
            if (ov > sv[t] || (ov == sv[t] && oi < si[t])) {
                sv[t] = ov;
                si[t] = oi;
            }
        }
        __syncthreads();
    }
    if (t == 0) dout[row] = si[0] * (N_SAMPLES / N_FRAMES);
}

// ---------------------------------------------------------------------------
// Kernel 3: out[row, t] = (t >= d) ? stems[row, t-d] / 256 : 0
// d is a multiple of 256; float4 chunks stay aligned and never straddle d.
// ---------------------------------------------------------------------------
__global__ __launch_bounds__(256) void shift_kernel(
    const float* __restrict__ stems,     // (512, 32768)
    const int*   __restrict__ dvals,     // (512)
    float*       __restrict__ out)       // (512, 32768)
{
    int row = blockIdx.y;
    int t = (blockIdx.x * 256 + threadIdx.x) * 4;
    int d = dvals[row];

    const float4* src = (const float4*)(stems + (size_t)row * N_SAMPLES);
    float4*       dst = (float4*)(out + (size_t)row * N_SAMPLES);

    float4 v;
    if (t >= d) {
        v = src[(t - d) >> 2];
        const float sc = 1.0f / 256.0f;
        v.x *= sc; v.y *= sc; v.z *= sc; v.w *= sc;
    } else {
        v = make_float4(0.f, 0.f, 0.f, 0.f);
    }
    dst[t >> 2] = v;
}

extern "C" void kernel_launch(void* const* d_in, const int* in_sizes, int n_in,
                              void* d_out, int out_size, void* d_ws, size_t ws_size,
                              hipStream_t stream) {
    const float* tl    = (const float*)d_in[0];  // time_latent (512,128)
    const float* stems = (const float*)d_in[1];  // (32,16,32768)
    // d_in[2] = targets — unused by the reference
    const float* W     = (const float*)d_in[3];  // (128,33)
    const float* b     = (const float*)d_in[4];  // (33)
    float* out = (float*)d_out;

    float* pos_hat = (float*)d_ws;
    int*   dvals   = (int*)((char*)d_ws + 32768);

    pos_kernel<<<N_FRAMES, 64, 0, stream>>>(pos_hat);
    argmax_kernel<<<N_ROWS, 128, 0, stream>>>(tl, W, b, pos_hat, dvals);
    shift_kernel<<<dim3(N_SAMPLES / (256 * 4), N_ROWS), 256, 0, stream>>>(stems, dvals, out);
}